// Round 10
// baseline (88.197 us; speedup 1.0000x reference)
//
#include <hip/hip_runtime.h>
#include <math.h>

// Soft silhouette renderer — R27 = R20 base + BRANCH-FREE 4-deep j-loop
// (singles/triples sort DISCARDED — R26 proved it net-negative even
// scratch-clean).
// verts: (4, 778, 3) f32   faces: (1538, 3) i32   out: (4, 320, 320) f32
//
// Verified-exact math core (R4, absmax 0.0):
//   area2 = fma(dx1, dy2, -round(dy1*dx2)) — matches the reference
//   evaluator's contraction; degenerate faces (sgn=0 -> 1/8 veil, i1==i2
//   sliver -> sigma=1/2 ridge) fall out of the generic edge code.
//
// R26 post-mortem: component-wise selects fixed the scratch demotion
// (WRITE_SIZE anomaly gone, silhouette back <40us) but the sort is a net
// +5us vs R20 — trans-reduction didn't pay. That falsifies the
// "trans-issue-bound" model: issue arithmetic gives only ~14us total
// (1.4M face-visits x ~24 instr / 1024 SIMDs), yet silhouette runs ~38us.
// The gap is NOT issue. Revised theory: the per-body
// `if (live && m > -T_CUT)` branches. Mixed waves (common: band faces
// cover most of the tile) save nothing from predication — every instr
// issues anyway — while the branches (a) block the compiler from
// software-pipelining the fma->exp->mul->rcp chains (~70cy exposed
// latency per body), (b) add 2-3 exec-mask ops per body.
//
// R27: branch-free 4-deep j-loop:
//  * f = max(1 - rcp(da*db*dc), 1e-6) is total-range-safe: far-outside
//    edge -> exp=inf -> d=inf -> rcp=0 -> f=1 (no-op); deep-inside ->
//    f=1e-6 (= reference clip). d>=1 always -> no NaN. m-gate and live
//    predication DELETED; wave ballot-exit every 4 faces retained
//    (saturated lanes multiplying further is strictly more accurate).
//  * 4x unroll, tail-guards as wave-uniform scalar selects
//    (f_k = (j_k<n) ? f_k : 1), loads grouped 2+2 to bound VGPR pressure.
//  * acc *= (f0*f1)*(f2*f3) — tree product, 2 muls parallel.
// With zero branches the scheduler can interleave the 4 bodies' trans
// chains — converting exposed latency into throughput.
// Staging / alive-vote / cover-fold / chunking: R20 verbatim.
// LDS: 3*388*16B + 1KB ~= 19.7KB -> 8 blocks/CU.
//
// Error budget vs 2e-2 tolerance (absmax floor 0.00390625 = one bf16 ulp
// since R5): cull skip <= 1538*e^-12 = 9.4e-3 worst-case; branchless
// factor ~1e-7/face; saturation cut 2.3e-6; product rounding ~1e-4
// (incl. tree-product reassociation).

#define IMG_S 320
#define N_FACES 1538
#define N_VERTS 778
#define N_BATCH 4
#define FP 1600            // padded face stride in ws
#define TILE 8
#define CHUNK_F 384        // faces per chunk (4 chunks: 384,384,384,386)
#define N_CHUNKS 4
#define MAXB 388           // LDS band capacity (>= max chunk size 386)
#define NWAVE 4
#define INV_SIGMA 100.0f
#define T_CUT 12.0f
#define ACC_CUT_P 2.2603294e-6f    // e^-13, product-domain saturation
#define LOG2_1EM6 -19.9315686f     // log2(1e-6)

__global__ __launch_bounds__(256)
void prep_faces(const float* __restrict__ verts,
                const int* __restrict__ faces,
                float4* __restrict__ gE0,
                float4* __restrict__ gE1,
                float4* __restrict__ gE2)
{
    const int f = blockIdx.x * 256 + threadIdx.x;
    const int b = blockIdx.z;
    if (f >= N_FACES) return;

    const float* vb = verts + (size_t)b * N_VERTS * 3;
    const int i0 = faces[f * 3 + 0];
    const int i1 = faces[f * 3 + 1];
    const int i2 = faces[f * 3 + 2];
    const float x0 = vb[i0 * 3 + 0], y0 = -vb[i0 * 3 + 1];
    const float x1 = vb[i1 * 3 + 0], y1 = -vb[i1 * 3 + 1];
    const float x2 = vb[i2 * 3 + 0], y2 = -vb[i2 * 3 + 1];

    // VERIFIED-EXACT (R4): fma-contracted area2 — do not change.
    const float dx1 = x1 - x0, dy1 = y1 - y0;
    const float dx2 = x2 - x0, dy2 = y2 - y0;
    const float area2 = __builtin_fmaf(dx1, dy2, -__fmul_rn(dy1, dx2));
    const float sgn = (area2 > 0.0f) ? 1.0f : ((area2 < 0.0f) ? -1.0f : 0.0f);

    const size_t o = (size_t)b * FP + f;
    {   // edge v0 -> v1
        const float ex = x1 - x0, ey = y1 - y0;
        const float s = sgn * INV_SIGMA / (sqrtf(ex * ex + ey * ey) + 1e-8f);
        gE0[o] = make_float4(-s * ey, s * ex, s * (ey * x0 - ex * y0), 0.0f);
    }
    {   // edge v1 -> v2
        const float ex = x2 - x1, ey = y2 - y1;
        const float s = sgn * INV_SIGMA / (sqrtf(ex * ex + ey * ey) + 1e-8f);
        gE1[o] = make_float4(-s * ey, s * ex, s * (ey * x1 - ex * y1), 0.0f);
    }
    {   // edge v2 -> v0
        const float ex = x0 - x2, ey = y0 - y2;
        const float s = sgn * INV_SIGMA / (sqrtf(ex * ex + ey * ey) + 1e-8f);
        gE2[o] = make_float4(-s * ey, s * ex, s * (ey * x2 - ex * y2), 0.0f);
    }
}

__global__ __launch_bounds__(256)
void silhouette_ws(const float4* __restrict__ gE0,
                   const float4* __restrict__ gE1,
                   const float4* __restrict__ gE2,
                   float* __restrict__ out)
{
    __shared__ float4 sE0[MAXB];   // compacted band-face edge payloads
    __shared__ float4 sE1[MAXB];
    __shared__ float4 sE2[MAXB];
    __shared__ float sAcc[256];
    __shared__ int sCount;
    __shared__ int sAlive;
    __shared__ int sCover;

    const int t    = threadIdx.x;
    const int wave = t >> 6;
    const int lane = t & 63;
    const int p    = t & 63;          // pixel id within 8x8 tile
    const int plx  = p & 7;
    const int ply  = p >> 3;
    const int b    = blockIdx.z;
    const int gx   = blockIdx.x * TILE + plx;
    const int gy   = blockIdx.y * TILE + ply;

    const float w  = 2.0f / IMG_S;
    const float px = (gx + 0.5f) * w - 1.0f;
    const float py = (gy + 0.5f) * w - 1.0f;
    const float cx = (blockIdx.x * TILE + 4) * w - 1.0f;
    const float cy = (blockIdx.y * TILE + 4) * w - 1.0f;
    const float rr = 3.5f * w;

    const float4* gb0 = gE0 + (size_t)b * FP;   // per-batch base
    const float4* gb1 = gE1 + (size_t)b * FP;
    const float4* gb2 = gE2 + (size_t)b * FP;

    float acc = 1.0f;   // product of (1-prob) over this wave's face subset
                        // (wave 0 also carries the cover factors)

    for (int c = 0; c < N_CHUNKS; ++c) {
        const int base = c * CHUNK_F;
        const int end  = (c == N_CHUNKS - 1) ? N_FACES : base + CHUNK_F;

        sAcc[t] = acc;
        if (t == 0) { sCount = 0; sAlive = 0; sCover = 0; }
        __syncthreads();   // B1: resets + partials visible

        const float tot = sAcc[p] * sAcc[p + 64] * sAcc[p + 128] * sAcc[p + 192];
        const bool alive = (tot > ACC_CUT_P);
        if (alive) sAlive = 1;               // benign same-value race
        __syncthreads();   // B2: vote final — break BEFORE staging
                           // (also fences prev chunk's sE reads from this
                           //  chunk's sE writes)

        if (sAlive == 0) break;   // uniform: every pixel saturated

        // ---- staging: classify faces, compact band PAYLOADS (R20) ----
        for (int fb = base; fb < end; fb += 256) {
            const int fc = fb + t;
            const bool vald = (fc < end);
            const int fcc = vald ? fc : (end - 1);
            const float4 e0 = gb0[fcc];      // coalesced vector loads
            const float4 e1 = gb1[fcc];
            const float4 e2 = gb2[fcc];
            const float c0 = fmaf(e0.x, cx, fmaf(e0.y, cy, e0.z));
            const float c1 = fmaf(e1.x, cx, fmaf(e1.y, cy, e1.z));
            const float c2 = fmaf(e2.x, cx, fmaf(e2.y, cy, e2.z));
            const float r0 = rr * (fabsf(e0.x) + fabsf(e0.y));
            const float r1 = rr * (fabsf(e1.x) + fabsf(e1.y));
            const float r2 = rr * (fabsf(e2.x) + fabsf(e2.y));
            const float m_hi = fminf(c0 + r0, fminf(c1 + r1, c2 + r2));
            const float m_lo = fminf(c0 - r0, fminf(c1 - r1, c2 - r2));
            const bool isCov  = vald && (m_lo > T_CUT);
            const bool isBand = vald && !isCov && (m_hi > -T_CUT);

            const unsigned long long mb = __ballot(isBand);
            int wbase = 0;
            if (lane == 0) {
                const int nw = __popcll(mb);
                if (nw) wbase = atomicAdd(&sCount, nw);
            }
            wbase = __shfl(wbase, 0);
            if (isBand) {
                const int pos = wbase + __popcll(mb & ((1ull << lane) - 1ull));
                sE0[pos] = e0;               // payload compaction (R19)
                sE1[pos] = e1;
                sE2[pos] = e2;
            }
            const unsigned long long mc = __ballot(isCov);
            if (lane == 0) {
                const int ncv = __popcll(mc);
                if (ncv) atomicAdd(&sCover, ncv);
            }
        }
        __syncthreads();   // B3: compaction + cover count final

        const float coverF = exp2f((float)sCover * LOG2_1EM6);
        if (wave == 0) acc *= coverF;

        // ---- j-loop: branch-free, 4-deep, tree-product ----
        const int n = sCount;
        int j = wave;
        while (j < n) {
            if (__ballot(acc > ACC_CUT_P) == 0ull) break;  // wave saturated
            const int ja = j;
            const int jb = j + NWAVE;
            const int jc = j + 2 * NWAVE;
            const int jd = j + 3 * NWAVE;
            const int jbc = (jb < n) ? jb : ja;   // wave-uniform clamps
            const int jcc = (jc < n) ? jc : ja;
            const int jdc = (jd < n) ? jd : ja;

            float f0, f1, f2, f3;
            {   // pair 0+1
                const float4 A0 = sE0[ja],  A1 = sE1[ja],  A2 = sE2[ja];
                const float4 B0 = sE0[jbc], B1 = sE1[jbc], B2 = sE2[jbc];
                const float xa0 = fmaf(A0.x, px, fmaf(A0.y, py, A0.z));
                const float xb0 = fmaf(A1.x, px, fmaf(A1.y, py, A1.z));
                const float xc0 = fmaf(A2.x, px, fmaf(A2.y, py, A2.z));
                const float xa1 = fmaf(B0.x, px, fmaf(B0.y, py, B0.z));
                const float xb1 = fmaf(B1.x, px, fmaf(B1.y, py, B1.z));
                const float xc1 = fmaf(B2.x, px, fmaf(B2.y, py, B2.z));
                const float d0 = (1.0f + __expf(-xa0)) *
                                 (1.0f + __expf(-xb0)) *
                                 (1.0f + __expf(-xc0));
                const float d1 = (1.0f + __expf(-xa1)) *
                                 (1.0f + __expf(-xb1)) *
                                 (1.0f + __expf(-xc1));
                f0 = fmaxf(1.0f - __builtin_amdgcn_rcpf(d0), 1e-6f);
                f1 = fmaxf(1.0f - __builtin_amdgcn_rcpf(d1), 1e-6f);
            }
            {   // pair 2+3
                const float4 C0 = sE0[jcc], C1 = sE1[jcc], C2 = sE2[jcc];
                const float4 D0 = sE0[jdc], D1 = sE1[jdc], D2 = sE2[jdc];
                const float xa2 = fmaf(C0.x, px, fmaf(C0.y, py, C0.z));
                const float xb2 = fmaf(C1.x, px, fmaf(C1.y, py, C1.z));
                const float xc2 = fmaf(C2.x, px, fmaf(C2.y, py, C2.z));
                const float xa3 = fmaf(D0.x, px, fmaf(D0.y, py, D0.z));
                const float xb3 = fmaf(D1.x, px, fmaf(D1.y, py, D1.z));
                const float xc3 = fmaf(D2.x, px, fmaf(D2.y, py, D2.z));
                const float d2 = (1.0f + __expf(-xa2)) *
                                 (1.0f + __expf(-xb2)) *
                                 (1.0f + __expf(-xc2));
                const float d3 = (1.0f + __expf(-xa3)) *
                                 (1.0f + __expf(-xb3)) *
                                 (1.0f + __expf(-xc3));
                f2 = fmaxf(1.0f - __builtin_amdgcn_rcpf(d2), 1e-6f);
                f3 = fmaxf(1.0f - __builtin_amdgcn_rcpf(d3), 1e-6f);
            }
            // tail neutralization: wave-uniform scalar selects (no branch)
            f1 = (jb < n) ? f1 : 1.0f;
            f2 = (jc < n) ? f2 : 1.0f;
            f3 = (jd < n) ? f3 : 1.0f;
            acc *= (f0 * f1) * (f2 * f3);
            j += 4 * NWAVE;
        }
        // no B4: next chunk's sE writes happen after its B2, which every
        // wave passes only after finishing this j-loop.
    }

    // final reduction + output (loop exits are block-uniform)
    sAcc[t] = acc;
    __syncthreads();
    if (t < 64) {
        const float tot = sAcc[p] * sAcc[p + 64] * sAcc[p + 128] * sAcc[p + 192];
        out[(size_t)b * (IMG_S * IMG_S) + (size_t)gy * IMG_S + gx] = 1.0f - tot;
    }
}

extern "C" void kernel_launch(void* const* d_in, const int* in_sizes, int n_in,
                              void* d_out, int out_size, void* d_ws, size_t ws_size,
                              hipStream_t stream) {
    const float* verts = (const float*)d_in[0];
    const int* faces = (const int*)d_in[1];
    float* out = (float*)d_out;

    // ws layout: 3 arrays of float4[N_BATCH * FP]  (3 * 4*1600*16B = 307 KB)
    float4* gE0 = (float4*)d_ws;
    float4* gE1 = gE0 + (size_t)N_BATCH * FP;
    float4* gE2 = gE1 + (size_t)N_BATCH * FP;

    dim3 pgrid((N_FACES + 255) / 256, 1, N_BATCH);
    prep_faces<<<pgrid, 256, 0, stream>>>(verts, faces, gE0, gE1, gE2);

    dim3 grid(IMG_S / TILE, IMG_S / TILE, N_BATCH);
    silhouette_ws<<<grid, 256, 0, stream>>>(gE0, gE1, gE2, out);
}

// Round 11
// 83.495 us; speedup vs baseline: 1.0563x; 1.0563x over previous
//
#include <hip/hip_runtime.h>
#include <math.h>

// Soft silhouette renderer — R28 = R20 VERBATIM + the missing half of the
// staging SAT: per-face tile-bbox prune (4B packed, coalesced) inside the
// unchanged staging sweep.
// verts: (4, 778, 3) f32   faces: (1538, 3) i32   out: (4, 320, 320) f32
//
// Verified-exact math core (R4, absmax 0.0):
//   area2 = fma(dx1, dy2, -round(dy1*dx2)) — matches the reference
//   evaluator's contraction; degenerate faces (sgn=0 -> 1/8 veil, i1==i2
//   sliver -> sigma=1/2 ridge) fall out of the generic edge code.
//
// R27 post-mortem (88.2us, silhouette ~46): branch-free 4-deep REGRESSED
// — falsifies "branches block pipelining". With R26's null on trans
// reduction, the inverted picture: the per-body m-gate is a NET WIN
// (whole-wave s_cbranch_execz skips staging false-positives), and exp
// throughput is not the j-loop limit. R20 (81.7) remains unbeaten by any
// j-loop restructure. Remaining levers: fewer face-visits / cheaper
// staging.
//
// R28 theory: R20's staging test min_i(c_i + r_i) > -T is only the
// half-plane HALF of a separating-axis test — it misses box-axis
// separators. Sliver triangles (common with random index triples) pass
// for tiles far along their thin inflated wedge. The missing SAT half is
// exactly R22's per-face tile bbox (inflated-halfplane corner math,
// conservative-verified on this data by R22's passing run). R22 failed
// by REPLACING the coalesced sweep with a scattered gather; R28 ADDS the
// bbox as a 4B coalesced prune inside R20's staging:
//  * prep packs (tx0,tx1,ty0,ty1) u8 into one uint per face;
//    degenerate/near-parallel corners -> full-image bbox.
//  * staging: hit = tx/ty within bbox; isCov &&= hit, isBand &&= hit.
// Pruned faces have per-pixel m < -T_CUT for EVERY tile pixel (their
// inflated region misses the tile), so they contributed nothing through
// R20's j-loop gate: output is BIT-IDENTICAL to R20 (order of surviving
// faces preserved). Strictly bounded-risk: cost is 1 coalesced 4B load +
// ~6 int ops per face-classification.
// Everything else (staging, alive-vote, cover fold, chunking, 2x-unroll
// gated j-loop, live gate): R20 byte-for-byte.
// LDS: 3*388*16B + 1KB ~= 19.7KB -> 8 blocks/CU.
//
// Error budget vs 2e-2 tolerance (absmax floor 0.00390625 = one bf16 ulp
// since R5): identical to R20 — cull skip <= 1538*e^-12 = 9.4e-3
// worst-case; branchless factor ~1e-7/face; saturation cut 2.3e-6;
// product rounding ~1e-4.

#define IMG_S 320
#define N_TILES 40         // IMG_S / TILE
#define N_FACES 1538
#define N_VERTS 778
#define N_BATCH 4
#define FP 1600            // padded face stride in ws
#define TILE 8
#define CHUNK_F 384        // faces per chunk (4 chunks: 384,384,384,386)
#define N_CHUNKS 4
#define MAXB 388           // LDS band capacity (>= max chunk size 386)
#define NWAVE 4
#define INV_SIGMA 100.0f
#define T_CUT 12.0f
#define ACC_CUT_P 2.2603294e-6f    // e^-13, product-domain saturation
#define LOG2_1EM6 -19.9315686f     // log2(1e-6)

__global__ __launch_bounds__(256)
void prep_faces(const float* __restrict__ verts,
                const int* __restrict__ faces,
                float4* __restrict__ gE0,
                float4* __restrict__ gE1,
                float4* __restrict__ gE2,
                unsigned int* __restrict__ gBB)
{
    const int f = blockIdx.x * 256 + threadIdx.x;
    const int b = blockIdx.z;
    if (f >= N_FACES) return;

    const float* vb = verts + (size_t)b * N_VERTS * 3;
    const int i0 = faces[f * 3 + 0];
    const int i1 = faces[f * 3 + 1];
    const int i2 = faces[f * 3 + 2];
    const float x0 = vb[i0 * 3 + 0], y0 = -vb[i0 * 3 + 1];
    const float x1 = vb[i1 * 3 + 0], y1 = -vb[i1 * 3 + 1];
    const float x2 = vb[i2 * 3 + 0], y2 = -vb[i2 * 3 + 1];

    // VERIFIED-EXACT (R4): fma-contracted area2 — do not change.
    const float dx1 = x1 - x0, dy1 = y1 - y0;
    const float dx2 = x2 - x0, dy2 = y2 - y0;
    const float area2 = __builtin_fmaf(dx1, dy2, -__fmul_rn(dy1, dx2));
    const float sgn = (area2 > 0.0f) ? 1.0f : ((area2 < 0.0f) ? -1.0f : 0.0f);

    const size_t o = (size_t)b * FP + f;
    float4 e0, e1, e2;
    {   // edge v0 -> v1
        const float ex = x1 - x0, ey = y1 - y0;
        const float s = sgn * INV_SIGMA / (sqrtf(ex * ex + ey * ey) + 1e-8f);
        e0 = make_float4(-s * ey, s * ex, s * (ey * x0 - ex * y0), 0.0f);
    }
    {   // edge v1 -> v2
        const float ex = x2 - x1, ey = y2 - y1;
        const float s = sgn * INV_SIGMA / (sqrtf(ex * ex + ey * ey) + 1e-8f);
        e1 = make_float4(-s * ey, s * ex, s * (ey * x1 - ex * y1), 0.0f);
    }
    {   // edge v2 -> v0
        const float ex = x0 - x2, ey = y0 - y2;
        const float s = sgn * INV_SIGMA / (sqrtf(ex * ex + ey * ey) + 1e-8f);
        e2 = make_float4(-s * ey, s * ex, s * (ey * x2 - ex * y2), 0.0f);
    }
    gE0[o] = e0;
    gE1[o] = e1;
    gE2[o] = e2;

    // ---- conservative tile bbox (R22's verified corner math) ----
    const float pw = 2.0f / IMG_S;
    const float rr = 3.5f * pw;
    const float r0 = rr * (fabsf(e0.x) + fabsf(e0.y));
    const float r1 = rr * (fabsf(e1.x) + fabsf(e1.y));
    const float r2 = rr * (fabsf(e2.x) + fabsf(e2.y));
    const float C0 = e0.z + T_CUT + r0 + 0.5f;
    const float C1 = e1.z + T_CUT + r1 + 0.5f;
    const float C2 = e2.z + T_CUT + r2 + 0.5f;

    float xmn = 1e30f, xmx = -1e30f, ymn = 1e30f, ymx = -1e30f;
    bool ok = true;
    {   // corner l0 x l1
        const float ww = e0.x * e1.y - e0.y * e1.x;
        if (fabsf(ww) < 1e-3f) ok = false;
        else {
            const float iw = 1.0f / ww;
            const float x = (e0.y * C1 - C0 * e1.y) * iw;
            const float y = (C0 * e1.x - e0.x * C1) * iw;
            xmn = fminf(xmn, x); xmx = fmaxf(xmx, x);
            ymn = fminf(ymn, y); ymx = fmaxf(ymx, y);
        }
    }
    {   // corner l1 x l2
        const float ww = e1.x * e2.y - e1.y * e2.x;
        if (fabsf(ww) < 1e-3f) ok = false;
        else {
            const float iw = 1.0f / ww;
            const float x = (e1.y * C2 - C1 * e2.y) * iw;
            const float y = (C1 * e2.x - e1.x * C2) * iw;
            xmn = fminf(xmn, x); xmx = fmaxf(xmx, x);
            ymn = fminf(ymn, y); ymx = fmaxf(ymx, y);
        }
    }
    {   // corner l2 x l0
        const float ww = e2.x * e0.y - e2.y * e0.x;
        if (fabsf(ww) < 1e-3f) ok = false;
        else {
            const float iw = 1.0f / ww;
            const float x = (e2.y * C0 - C2 * e0.y) * iw;
            const float y = (C2 * e0.x - e2.x * C0) * iw;
            xmn = fminf(xmn, x); xmx = fmaxf(xmx, x);
            ymn = fminf(ymn, y); ymx = fmaxf(ymx, y);
        }
    }
    if (!ok || !(xmn <= xmx) || !(ymn <= ymx)) {   // degenerate -> full image
        xmn = -1.0f; xmx = 1.0f; ymn = -1.0f; ymx = 1.0f;
    }
    xmn = fmaxf(xmn, -1.0f); xmx = fminf(xmx, 1.0f);
    ymn = fmaxf(ymn, -1.0f); ymx = fminf(ymx, 1.0f);

    // tile center of tx: (tx*8+4)*pw - 1  ->  tx = (((x+1)*160)-4)/8
    const int tx0 = max(0,  (int)floorf(((xmn + 1.0f) * 160.0f - 4.0f) * 0.125f) - 1);
    const int tx1 = min(N_TILES - 1, (int)ceilf(((xmx + 1.0f) * 160.0f - 4.0f) * 0.125f) + 1);
    const int ty0 = max(0,  (int)floorf(((ymn + 1.0f) * 160.0f - 4.0f) * 0.125f) - 1);
    const int ty1 = min(N_TILES - 1, (int)ceilf(((ymx + 1.0f) * 160.0f - 4.0f) * 0.125f) + 1);

    gBB[o] = (unsigned)tx0 | ((unsigned)max(tx1, tx0) << 8) |
             ((unsigned)ty0 << 16) | ((unsigned)max(ty1, ty0) << 24);
}

__global__ __launch_bounds__(256)
void silhouette_ws(const float4* __restrict__ gE0,
                   const float4* __restrict__ gE1,
                   const float4* __restrict__ gE2,
                   const unsigned int* __restrict__ gBB,
                   float* __restrict__ out)
{
    __shared__ float4 sE0[MAXB];   // compacted band-face edge payloads
    __shared__ float4 sE1[MAXB];
    __shared__ float4 sE2[MAXB];
    __shared__ float sAcc[256];
    __shared__ int sCount;
    __shared__ int sAlive;
    __shared__ int sCover;

    const int t    = threadIdx.x;
    const int wave = t >> 6;
    const int lane = t & 63;
    const int p    = t & 63;          // pixel id within 8x8 tile
    const int plx  = p & 7;
    const int ply  = p >> 3;
    const int b    = blockIdx.z;
    const int tx   = blockIdx.x;
    const int ty   = blockIdx.y;
    const int gx   = tx * TILE + plx;
    const int gy   = ty * TILE + ply;

    const float w  = 2.0f / IMG_S;
    const float px = (gx + 0.5f) * w - 1.0f;
    const float py = (gy + 0.5f) * w - 1.0f;
    const float cx = (tx * TILE + 4) * w - 1.0f;
    const float cy = (ty * TILE + 4) * w - 1.0f;
    const float rr = 3.5f * w;

    const float4* gb0 = gE0 + (size_t)b * FP;   // per-batch base
    const float4* gb1 = gE1 + (size_t)b * FP;
    const float4* gb2 = gE2 + (size_t)b * FP;
    const unsigned int* bbb = gBB + (size_t)b * FP;

    float acc = 1.0f;   // product of (1-prob) over this wave's face subset
                        // (wave 0 also carries the cover factors)

    for (int c = 0; c < N_CHUNKS; ++c) {
        const int base = c * CHUNK_F;
        const int end  = (c == N_CHUNKS - 1) ? N_FACES : base + CHUNK_F;

        sAcc[t] = acc;
        if (t == 0) { sCount = 0; sAlive = 0; sCover = 0; }
        __syncthreads();   // B1: resets + partials visible

        const float tot = sAcc[p] * sAcc[p + 64] * sAcc[p + 128] * sAcc[p + 192];
        const bool alive = (tot > ACC_CUT_P);
        if (alive) sAlive = 1;               // benign same-value race
        __syncthreads();   // B2: vote final — break BEFORE staging
                           // (also fences prev chunk's sE reads from this
                           //  chunk's sE writes)

        if (sAlive == 0) break;   // uniform: every pixel saturated

        // ---- staging: classify faces, compact band PAYLOADS (R20) ----
        for (int fb = base; fb < end; fb += 256) {
            const int fc = fb + t;
            const bool vald = (fc < end);
            const int fcc = vald ? fc : (end - 1);
            const float4 e0 = gb0[fcc];      // coalesced vector loads
            const float4 e1 = gb1[fcc];
            const float4 e2 = gb2[fcc];
            const unsigned bb = bbb[fcc];    // packed tile bbox (4B, coal.)
            // SAT box-axis half: prune corner/wedge false positives.
            const bool hit =
                (tx >= (int)(bb & 255u))         && (tx <= (int)((bb >> 8) & 255u)) &&
                (ty >= (int)((bb >> 16) & 255u)) && (ty <= (int)(bb >> 24));
            const float c0 = fmaf(e0.x, cx, fmaf(e0.y, cy, e0.z));
            const float c1 = fmaf(e1.x, cx, fmaf(e1.y, cy, e1.z));
            const float c2 = fmaf(e2.x, cx, fmaf(e2.y, cy, e2.z));
            const float r0 = rr * (fabsf(e0.x) + fabsf(e0.y));
            const float r1 = rr * (fabsf(e1.x) + fabsf(e1.y));
            const float r2 = rr * (fabsf(e2.x) + fabsf(e2.y));
            const float m_hi = fminf(c0 + r0, fminf(c1 + r1, c2 + r2));
            const float m_lo = fminf(c0 - r0, fminf(c1 - r1, c2 - r2));
            const bool isCov  = vald && hit && (m_lo > T_CUT);
            const bool isBand = vald && hit && !isCov && (m_hi > -T_CUT);

            const unsigned long long mb = __ballot(isBand);
            int wbase = 0;
            if (lane == 0) {
                const int nw = __popcll(mb);
                if (nw) wbase = atomicAdd(&sCount, nw);
            }
            wbase = __shfl(wbase, 0);
            if (isBand) {
                const int pos = wbase + __popcll(mb & ((1ull << lane) - 1ull));
                sE0[pos] = e0;               // payload compaction (R19)
                sE1[pos] = e1;
                sE2[pos] = e2;
            }
            const unsigned long long mc = __ballot(isCov);
            if (lane == 0) {
                const int ncv = __popcll(mc);
                if (ncv) atomicAdd(&sCover, ncv);
            }
        }
        __syncthreads();   // B3: compaction + cover count final

        const float coverF = exp2f((float)sCover * LOG2_1EM6);
        bool live = alive && (acc * coverF > ACC_CUT_P);
        if (wave == 0) acc *= coverF;

        const int n = sCount;
        int j = wave;
        while (j < n) {
            if (__ballot(live) == 0ull) break;   // whole wave saturated
            const int j1 = j + NWAVE;
            const int j1c = (j1 < n) ? j1 : j;
            // issue both iterations' LDS broadcasts before any compute
            const float4 A0 = sE0[j],   A1 = sE1[j],   A2 = sE2[j];
            const float4 B0 = sE0[j1c], B1 = sE1[j1c], B2 = sE2[j1c];
            {   // iteration 0 — branchless band body
                const float xa = fmaf(A0.x, px, fmaf(A0.y, py, A0.z));
                const float xb = fmaf(A1.x, px, fmaf(A1.y, py, A1.z));
                const float xc = fmaf(A2.x, px, fmaf(A2.y, py, A2.z));
                const float m = fminf(xa, fminf(xb, xc));
                if (live && m > -T_CUT) {
                    const float da = 1.0f + __expf(-xa);
                    const float db = 1.0f + __expf(-xb);
                    const float dc = 1.0f + __expf(-xc);
                    const float f = fmaxf(
                        1.0f - __builtin_amdgcn_rcpf(da * db * dc), 1e-6f);
                    acc *= f;
                    live = (acc > ACC_CUT_P);
                }
            }
            if (j1 < n) {   // iteration 1
                const float xa = fmaf(B0.x, px, fmaf(B0.y, py, B0.z));
                const float xb = fmaf(B1.x, px, fmaf(B1.y, py, B1.z));
                const float xc = fmaf(B2.x, px, fmaf(B2.y, py, B2.z));
                const float m = fminf(xa, fminf(xb, xc));
                if (live && m > -T_CUT) {
                    const float da = 1.0f + __expf(-xa);
                    const float db = 1.0f + __expf(-xb);
                    const float dc = 1.0f + __expf(-xc);
                    const float f = fmaxf(
                        1.0f - __builtin_amdgcn_rcpf(da * db * dc), 1e-6f);
                    acc *= f;
                    live = (acc > ACC_CUT_P);
                }
            }
            j += 2 * NWAVE;
        }
        // no B4: next chunk's sE writes happen after its B2, which every
        // wave passes only after finishing this j-loop.
    }

    // final reduction + output (loop exits are block-uniform)
    sAcc[t] = acc;
    __syncthreads();
    if (t < 64) {
        const float tot = sAcc[p] * sAcc[p + 64] * sAcc[p + 128] * sAcc[p + 192];
        out[(size_t)b * (IMG_S * IMG_S) + (size_t)gy * IMG_S + gx] = 1.0f - tot;
    }
}

extern "C" void kernel_launch(void* const* d_in, const int* in_sizes, int n_in,
                              void* d_out, int out_size, void* d_ws, size_t ws_size,
                              hipStream_t stream) {
    const float* verts = (const float*)d_in[0];
    const int* faces = (const int*)d_in[1];
    float* out = (float*)d_out;

    // ws layout:
    //   gE0/gE1/gE2 : 3 x 4*1600 float4 = 307,200 B
    //   gBB         : 4*1600 uint       =  25,600 B
    float4* gE0 = (float4*)d_ws;
    float4* gE1 = gE0 + (size_t)N_BATCH * FP;
    float4* gE2 = gE1 + (size_t)N_BATCH * FP;
    unsigned int* gBB = (unsigned int*)(gE2 + (size_t)N_BATCH * FP);

    dim3 pgrid((N_FACES + 255) / 256, 1, N_BATCH);
    prep_faces<<<pgrid, 256, 0, stream>>>(verts, faces, gE0, gE1, gE2, gBB);

    dim3 grid(IMG_S / TILE, IMG_S / TILE, N_BATCH);
    silhouette_ws<<<grid, 256, 0, stream>>>(gE0, gE1, gE2, gBB, out);
}